// Round 8
// baseline (133.014 us; speedup 1.0000x reference)
//
#include <hip/hip_runtime.h>

// OESNN_SEPhIA_MultiTiled2: 32-step recurrent SNN, B=8192.
// R9b: resubmit of R9 (round-7 bench died on container acquisition, not the
// kernel) with one pressure refinement: the role-select input is a single
// scalar consumed immediately by its two fmas (no u[18] array), trimming ~18
// regs of peak pressure so the <=128-VGPR fit at (256,4) is robust.
//
// Design (R9): 32 lanes/elem, 4096 waves = 4 waves/SIMD, ONE uniform
// unmasked pipeline for all lanes. Lane g<18 owns L0 channel g; lanes
// 18..31 own L1 output (g-18), 26..31 duplicating outputs 0..5 (identical
// state -> benign duplicate stores). Per iteration each lane: input select
// (x*1e-4 vs pw(t-1)), 36-fma even/odd dot with 36 resident weight regs,
// LIF (role-constant threshold), output select (role-constant hi/lo),
// 2 stores, 18-shfl exchange feeding the NEXT iteration's L1 (lag-1
// software pipeline, 33 iters; pwall zero-init keeps mem1 == 0 through
// iter 0, matching the reference's zero initial state).
// Evidence basis R2..R8: all structures deliver 8 elems/SIMD-iter; only
// per-elem issue and exposed short latencies vary. Masked phases (R4/R6)
// and half-column splits (R7/R8) raised per-elem issue; this design gives
// ~160 instr/wave-iter for 2 elems at 4 waves/SIMD.
// Numerics op-identical to the passing R2/R6 kernels: p = x*1e-4 single
// rounding, ascending-w single-accumulator fma chains, c = (se-so)*dd,
// select-based LIF, pon/poff precompute verbatim, pw moved by shfl.

namespace {
constexpr int Tn = 32;
constexpr int Bn = 8192;
constexpr int O_PW = 0;                       // spks0 (= pw0) [T,B,18]
constexpr int O_S1 = Tn * Bn * 18;            // spks1 [T,B,8]
constexpr int O_M0 = O_S1 + Tn * Bn * 8;      // mems0 [T,B,18]
constexpr int O_M1 = O_M0 + Tn * Bn * 18;     // mems1 [T,B,8]
}

__global__ __launch_bounds__(256, 4)
void oesnn_kernel(const float* __restrict__ x_in,
                  const float* __restrict__ W0g,   // [2,18,18]
                  const float* __restrict__ d0g,   // [2,9]
                  const float* __restrict__ W1g,   // [1,18,16]
                  const float* __restrict__ d1g,   // [1,8]
                  const float* __restrict__ peakg, // [36]
                  float* __restrict__ out)
{
    const int lt  = threadIdx.x & 63;         // lane in wave
    const int tid = blockIdx.x * 256 + threadIdx.x;
    const int b   = tid >> 5;                 // batch element (32 lanes/elem)
    const int g   = tid & 31;                 // lane within batch group
    const bool l0 = (g < 18);
    const int  o  = l0 ? 0 : ((g < 26) ? (g - 18) : (g - 26));  // L1 output (dup)
    const int  tl = l0 ? (g / 9) : 0;         // L0 tile; 0 keeps L1 addrs valid

    // ---------------- per-lane weight preload (36 regs, uniform arrays) ----
    float wA[18], wB[18];
    float dd, hi, lo, th;
    if (l0) {
        const int jc = g % 9;
        dd = d0g[tl * 9 + jc];
        th = 0.55f;
        #pragma unroll
        for (int w = 0; w < 18; ++w) {
            const float2 pr = *(const float2*)(W0g + ((tl * 18 + w) * 18 + 2 * jc));
            wA[w] = pr.x;
            wB[w] = pr.y;
        }
        // pw0 takes exactly two values per channel: precompute via the
        // reference's complex-division -> abs -> square path (verbatim R2).
        const int c = g;
        const float wl    = 1550.0f + 0.8f * (float)c;
        const float halfw = 0.5f * (wl * 1e3f / 15000.0f);
        const float amp   = sqrtf((exp10f(peakg[c] / 10.0f) / 1000.0f) * 1e6f);
        {   // spike = 0: lo = (0.1 + 0i)/(1 + 0i) * amp
            const float lr = 0.1f * amp;
            const float a  = sqrtf(lr * lr);
            lo = a * a;
        }
        {   // spike = 1: delta = -250 / (0.5*fwhm)
            const float delta = -250.0f / halfw;
            const float den = fmaf(delta, delta, 1.0f);
            const float qr  = fmaf(delta, delta, 0.1f) / den;     // (g + d^2)/den
            const float qi  = (delta - 0.1f * delta) / den;       // (d - g*d)/den
            const float lr = qr * amp, li = qi * amp;
            const float a  = sqrtf(fmaf(lr, lr, li * li));
            hi = a * a;
        }
    } else {
        dd = d1g[o];
        th = 0.25f;
        hi = 1.0f;
        lo = 0.0f;
        #pragma unroll
        for (int w = 0; w < 18; ++w) {
            const float2 pr = *(const float2*)(W1g + w * 16 + 2 * o);  // 8B-aligned
            wA[w] = pr.x;
            wB[w] = pr.y;
        }
    }

    // ---------------- state & pointers ----------------
    float mem = 0.f;                          // mem0[chan] or mem1[out]

    const float* xp = x_in + (size_t)b * 36 + tl * 18;
    // storeA: pw (L0) / spk1 (L1, lag-1); storeB: mem0 / mem1 (lag-1)
    float* pa = l0 ? (out + O_PW + (size_t)b * 18 + g)
                   : (out + O_S1 + (size_t)b * 8 + o - (size_t)Bn * 8);
    float* pb = l0 ? (out + O_M0 + (size_t)b * 18 + g)
                   : (out + O_M1 + (size_t)b * 8 + o - (size_t)Bn * 8);
    const int strA = l0 ? (Bn * 18) : (Bn * 8);   // per-iter advance (floats)

    // prefetch t=0 inputs (18 floats = 9x float2, 8B-aligned)
    float2 xv[9];
    #pragma unroll
    for (int k = 0; k < 9; ++k) xv[k] = *(const float2*)(xp + 2 * k);

    // pw of previous timestep (zero-init: keeps mem1 == 0 through iter 0,
    // since c1 = (0-0)*dd = 0 and LIF(0) = 0 -- matches reference init)
    float pwall[18];
    #pragma unroll
    for (int c = 0; c < 18; ++c) pwall[c] = 0.f;

    const int base32 = lt & ~31;   // first lane of this element's 32-lane group

    #pragma unroll 1
    for (int tt = 0; tt <= Tn; ++tt) {
        // ---- uniform even/odd column dot over the role-selected input:
        // L0 lanes consume p = x*1e-4 (rounded once, computed once per w),
        // L1 lanes consume pw(tt-1). Ascending w, single accumulator each. ----
        float se = 0.f, so = 0.f;
        #pragma unroll
        for (int k = 0; k < 9; ++k) {
            const float ua = l0 ? (xv[k].x * 1e-4f) : pwall[2 * k];
            se = fmaf(ua, wA[2 * k], se);
            so = fmaf(ua, wB[2 * k], so);
            const float ub = l0 ? (xv[k].y * 1e-4f) : pwall[2 * k + 1];
            se = fmaf(ub, wA[2 * k + 1], se);
            so = fmaf(ub, wB[2 * k + 1], so);
        }

        // prefetch next timestep (uniform; L1 lanes duplicate L0 addresses)
        if (tt + 1 < Tn) {
            xp += Bn * 36;
            #pragma unroll
            for (int k = 0; k < 9; ++k) xv[k] = *(const float2*)(xp + 2 * k);
        }

        // ---- uniform LIF + output select ----
        const float cc = (se - so) * dd;
        const float m2 = (mem > th) ? 0.0f : fmaf(0.95f, mem, cc);
        mem = m2;
        const float ov = (m2 > th) ? hi : lo;   // pw (L0) / spike (L1)

        // ---- exchange pw for next iteration's L1 (L0 lanes' ov == pw) ----
        #pragma unroll
        for (int c = 0; c < 18; ++c)
            pwall[c] = __shfl(ov, base32 + c, 64);

        // ---- 2 stores: L0 valid for tt<Tn, L1 for tt>0 (lag-1) ----
        const bool en = l0 ? (tt < Tn) : (tt > 0);
        if (en) {
            *pa = ov;
            *pb = m2;
        }
        pa += strA;
        pb += strA;
    }
}

extern "C" void kernel_launch(void* const* d_in, const int* in_sizes, int n_in,
                              void* d_out, int out_size, void* d_ws, size_t ws_size,
                              hipStream_t stream) {
    (void)in_sizes; (void)n_in; (void)out_size; (void)d_ws; (void)ws_size;
    const float* x  = (const float*)d_in[0];
    const float* W0 = (const float*)d_in[1];
    const float* d0 = (const float*)d_in[2];
    const float* W1 = (const float*)d_in[3];
    const float* d1 = (const float*)d_in[4];
    const float* pk = (const float*)d_in[5];
    float* out = (float*)d_out;

    dim3 grid(Bn * 32 / 256), block(256);   // 262144 threads = 4096 waves
    hipLaunchKernelGGL(oesnn_kernel, grid, block, 0, stream,
                       x, W0, d0, W1, d1, pk, out);
}

// Round 9
// 116.558 us; speedup vs baseline: 1.1412x; 1.1412x over previous
//
#include <hip/hip_runtime.h>

// OESNN_SEPhIA_MultiTiled2: 32-step recurrent SNN, B=8192.
// R10: the never-tested combination -- R2's verified 8-lane layout, weights
// PINNED in VGPRs, under a 256-VGPR cap. Cross-round evidence: R2 (cap 256,
// no pin) -> VGPR=120, demoted; R7/R8/R9 (caps 128/64) could never fit the
// weights regardless of pinning. The invariant ~2700 cyc/iter stall across
// 1/2/4 waves/SIMD matches per-iteration weight-reload vmcnt chains (shared
// vmem pipe -- more waves just queue more reloads, which is why TLP never
// helped and why R5's LDS table, ~120cyc chains, won only 5%).
// Fix: asm volatile("" : "+v") on all 154 loop-invariants AFTER preload,
// with __launch_bounds__(256,1) so the cap is 256 and the pinned set
// (~230 peak) fits. t-loop unrolled x2 with ping-pong x buffers (depth-2
// prefetch, statically indexed).
// Numerics are op-for-op the PASSING R2 kernel: p = x*1e-4 single rounding,
// ascending-w single-accumulator fma chains, separate even/odd sums,
// select-based LIF, pon/poff precompute verbatim, shfl gather (selection).

namespace {
constexpr int Tn = 32;
constexpr int Bn = 8192;
constexpr int O_PW = 0;                       // spks0 (= pw0) [T,B,18]
constexpr int O_S1 = Tn * Bn * 18;            // spks1 [T,B,8]
constexpr int O_M0 = O_S1 + Tn * Bn * 8;      // mems0 [T,B,18]
constexpr int O_M1 = O_M0 + Tn * Bn * 18;     // mems1 [T,B,8]
}

__global__ __launch_bounds__(256, 1)
void oesnn_kernel(const float* __restrict__ x_in,
                  const float* __restrict__ W0g,   // [2,18,18]
                  const float* __restrict__ d0g,   // [2,9]
                  const float* __restrict__ W1g,   // [1,18,16]
                  const float* __restrict__ d1g,   // [1,8]
                  const float* __restrict__ peakg, // [36]
                  float* __restrict__ out)
{
    const int lt  = threadIdx.x & 63;         // lane in wave
    const int tid = blockIdx.x * 256 + threadIdx.x;
    const int b   = tid >> 3;                 // batch element
    const int sub = tid & 7;                  // lane within batch group
    const int tl  = sub >> 2;                 // layer-0 tile (0/1)
    const int q   = sub & 3;                  // lane within tile
    const int j0  = (q == 0) ? 0 : (2 * q + 1);   // first in-tile channel
    const int nj  = (q == 0) ? 3 : 2;             // real channel count (pad to 3)

    // ---------------- per-lane weight preload into registers ----------------
    float w0e[3][18], w0o[3][18], dd0[3], pon[3], poff[3];
    #pragma unroll
    for (int j = 0; j < 3; ++j) {
        const int jc = (j < nj) ? (j0 + j) : j0;   // clamped dup stays in-lane
        dd0[j] = d0g[tl * 9 + jc];
        #pragma unroll
        for (int w = 0; w < 18; ++w) {
            const float2 p = *(const float2*)(W0g + ((tl * 18 + w) * 18 + 2 * jc));
            w0e[j][w] = p.x;
            w0o[j][w] = p.y;
        }
        // pw0 takes exactly two values per channel: precompute via the
        // reference's complex-division -> abs -> square path.
        const int c = tl * 9 + jc;
        const float wl    = 1550.0f + 0.8f * (float)c;
        const float halfw = 0.5f * (wl * 1e3f / 15000.0f);
        const float amp   = sqrtf((exp10f(peakg[c] / 10.0f) / 1000.0f) * 1e6f);
        {   // spike = 0: lo = (0.1 + 0i)/(1 + 0i) * amp
            const float lr = 0.1f * amp;
            const float a  = sqrtf(lr * lr);
            poff[j] = a * a;
        }
        {   // spike = 1: delta = -250 / (0.5*fwhm)
            const float delta = -250.0f / halfw;
            const float den = fmaf(delta, delta, 1.0f);
            const float qr  = fmaf(delta, delta, 0.1f) / den;     // (g + d^2)/den
            const float qi  = (delta - 0.1f * delta) / den;       // (d - g*d)/den
            const float lr = qr * amp, li = qi * amp;
            const float a  = sqrtf(fmaf(lr, lr, li * li));
            pon[j] = a * a;
        }
    }

    // layer-1: lane `sub` owns output channel o = sub (columns 2o, 2o+1).
    float w1e[18], w1o[18];
    #pragma unroll
    for (int w = 0; w < 18; ++w) {
        const float2 pp = *(const float2*)(W1g + w * 16 + 2 * sub);  // 8B-aligned
        w1e[w] = pp.x;
        w1o[w] = pp.y;
    }
    const float dd1 = d1g[sub];

    // ---------------- PIN all loop-invariants in VGPRs ----------------
    // Opaque no-op asm: the post-asm values cannot be rematerialized by
    // re-loading, so with the 256-VGPR cap of __launch_bounds__(256,1)
    // (~230 peak live) they stay register-resident across the t-loop.
    // This kills the per-iteration reload chains (R2: VGPR=120 < the ~190
    // needed; the compiler demoted voluntarily at cap 256 without the pin).
    float dd1p = dd1;
    #pragma unroll
    for (int j = 0; j < 3; ++j) {
        #pragma unroll
        for (int w = 0; w < 18; ++w) {
            asm volatile("" : "+v"(w0e[j][w]));
            asm volatile("" : "+v"(w0o[j][w]));
        }
        asm volatile("" : "+v"(dd0[j]));
        asm volatile("" : "+v"(pon[j]));
        asm volatile("" : "+v"(poff[j]));
    }
    #pragma unroll
    for (int w = 0; w < 18; ++w) {
        asm volatile("" : "+v"(w1e[w]));
        asm volatile("" : "+v"(w1o[w]));
    }
    asm volatile("" : "+v"(dd1p));

    // ---------------- state & pointers ----------------
    float mem0[3] = {0.f, 0.f, 0.f};
    float mem1 = 0.f;

    const float* xb = x_in + (size_t)b * 36 + tl * 18;
    float* opw = out + O_PW + (size_t)b * 18 + tl * 9 + j0;
    float* om0 = out + O_M0 + (size_t)b * 18 + tl * 9 + j0;
    float* os1 = out + O_S1 + (size_t)b * 8 + sub;
    float* om1 = out + O_M1 + (size_t)b * 8 + sub;

    const int basel = lt & ~7;

    // ---------------- depth-2 ping-pong x prefetch ----------------
    float2 xvA[9], xvB[9];
    {
        const float2* s0 = (const float2*)(xb);
        const float2* s1 = (const float2*)(xb + (size_t)Bn * 36);
        #pragma unroll
        for (int k = 0; k < 9; ++k) { xvA[k] = s0[k]; xvB[k] = s1[k]; }
    }

    // one timestep: consumes xv, refills it for tcur+2
    auto body = [&](float2 (&xv)[9], int tcur) {
        // p = x * 1e-4, rounded once (identical arithmetic to R2)
        float p[18];
        #pragma unroll
        for (int k = 0; k < 9; ++k) {
            p[2 * k]     = xv[k].x * 1e-4f;
            p[2 * k + 1] = xv[k].y * 1e-4f;
        }
        // refill this buffer for tcur+2 (deep prefetch)
        if (tcur + 2 < Tn) {
            const float2* s = (const float2*)(xb + (size_t)(tcur + 2) * Bn * 36);
            #pragma unroll
            for (int k = 0; k < 9; ++k) xv[k] = s[k];
        }

        // ---- layer 0: even/odd column dots, balanced PD, LIF, MRR power ----
        float pwv[3];
        #pragma unroll
        for (int j = 0; j < 3; ++j) {
            float se = 0.f, so = 0.f;
            #pragma unroll
            for (int w = 0; w < 18; ++w) {
                se = fmaf(p[w], w0e[j][w], se);
                so = fmaf(p[w], w0o[j][w], so);
            }
            const float c0 = (se - so) * dd0[j];
            const float m  = mem0[j];
            const float m2 = (m > 0.55f) ? 0.0f : fmaf(0.95f, m, c0);
            mem0[j] = m2;
            pwv[j]  = (m2 > 0.55f) ? pon[j] : poff[j];
        }

        // store pw0 / mem0 (guard the dup channel on 2-channel lanes)
        #pragma unroll
        for (int j = 0; j < 3; ++j) {
            if (j < nj) {
                opw[j] = pwv[j];
                om0[j] = mem0[j];
            }
        }

        // ---- cross-lane gather of all 18 pw values (verbatim R2) ----
        float pwall[18];
        #pragma unroll
        for (int c = 0; c < 18; ++c) {
            const int tlc = c / 9, jc2 = c % 9;
            const int qo  = (jc2 < 3) ? 0 : ((jc2 - 1) / 2);   // owner lane-in-tile
            const int st  = (qo == 0) ? 0 : (2 * qo + 1);
            const int r   = jc2 - st;                          // owner's reg index
            pwall[c] = __shfl(pwv[r], basel + tlc * 4 + qo, 64);
        }

        // ---- layer 1: ascending-w fma into this lane's 2 columns ----
        float i1e = 0.f, i1o = 0.f;
        #pragma unroll
        for (int w = 0; w < 18; ++w) {
            i1e = fmaf(pwall[w], w1e[w], i1e);
            i1o = fmaf(pwall[w], w1o[w], i1o);
        }

        const float c1 = (i1e - i1o) * dd1p;
        const float m  = mem1;
        const float m2 = (m > 0.25f) ? 0.0f : fmaf(0.95f, m, c1);
        mem1 = m2;
        *os1 = (m2 > 0.25f) ? 1.0f : 0.0f;   // 64 lanes -> 64 consecutive dwords
        *om1 = m2;

        opw += Bn * 18;
        om0 += Bn * 18;
        os1 += Bn * 8;
        om1 += Bn * 8;
    };

    #pragma unroll 1
    for (int t = 0; t < Tn; t += 2) {
        body(xvA, t);
        body(xvB, t + 1);
    }
}

extern "C" void kernel_launch(void* const* d_in, const int* in_sizes, int n_in,
                              void* d_out, int out_size, void* d_ws, size_t ws_size,
                              hipStream_t stream) {
    (void)in_sizes; (void)n_in; (void)out_size; (void)d_ws; (void)ws_size;
    const float* x  = (const float*)d_in[0];
    const float* W0 = (const float*)d_in[1];
    const float* d0 = (const float*)d_in[2];
    const float* W1 = (const float*)d_in[3];
    const float* d1 = (const float*)d_in[4];
    const float* pk = (const float*)d_in[5];
    float* out = (float*)d_out;

    dim3 grid(Bn * 8 / 256), block(256);   // 65536 threads = 1024 waves
    hipLaunchKernelGGL(oesnn_kernel, grid, block, 0, stream,
                       x, W0, d0, W1, d1, pk, out);
}